// Round 1
// baseline (19301.869 us; speedup 1.0000x reference)
//
#include <hip/hip_runtime.h>
#include <math.h>

// 3-layer LSTM (H=15) + linear head, B=32768, T=196.
// Structure: one thread per batch element; all h/c state in registers
// (fully unrolled so indices are compile-time -> no scratch); weights are
// wave-uniform -> compiler scalarizes to s_load feeding v_fma with SGPR src.
// Compute-bound on the vector ALU; 512 waves over 1024 SIMDs (50% ceiling).

#define HID 15
#define TT  196

__device__ __forceinline__ float fast_sigmoid(float x) {
    // 1/(1+e^-x); robust: e^+inf -> rcp -> 0
    return __builtin_amdgcn_rcpf(1.0f + __expf(-x));
}

__device__ __forceinline__ float fast_tanh(float x) {
    // tanh(x) = sign(x) * (1 - 2/(e^{2|x|}+1)); robust for large |x|
    float ax = fabsf(x);
    float e  = __expf(ax + ax);
    float t  = 1.0f - 2.0f * __builtin_amdgcn_rcpf(e + 1.0f);
    return copysignf(t, x);
}

// One LSTM cell step, input dim = HID (layers 1,2). xin/h/c are register arrays.
__device__ __forceinline__ void cell15(
    const float* __restrict__ wih, const float* __restrict__ whh,
    const float* __restrict__ bih, const float* __restrict__ bhh,
    const float* xin, float* h, float* c)
{
    float hn[HID];
#pragma unroll
    for (int j = 0; j < HID; ++j) {
        float gi = bih[j]         + bhh[j];
        float gf = bih[HID + j]   + bhh[HID + j];
        float gg = bih[2*HID + j] + bhh[2*HID + j];
        float go = bih[3*HID + j] + bhh[3*HID + j];
#pragma unroll
        for (int k = 0; k < HID; ++k) {
            gi = fmaf(wih[(j)*HID + k],         xin[k], gi);
            gf = fmaf(wih[(HID + j)*HID + k],   xin[k], gf);
            gg = fmaf(wih[(2*HID + j)*HID + k], xin[k], gg);
            go = fmaf(wih[(3*HID + j)*HID + k], xin[k], go);
        }
#pragma unroll
        for (int k = 0; k < HID; ++k) {
            gi = fmaf(whh[(j)*HID + k],         h[k], gi);
            gf = fmaf(whh[(HID + j)*HID + k],   h[k], gf);
            gg = fmaf(whh[(2*HID + j)*HID + k], h[k], gg);
            go = fmaf(whh[(3*HID + j)*HID + k], h[k], go);
        }
        float cn = fast_sigmoid(gf) * c[j] + fast_sigmoid(gi) * fast_tanh(gg);
        c[j]  = cn;
        hn[j] = fast_sigmoid(go) * fast_tanh(cn);
    }
#pragma unroll
    for (int j = 0; j < HID; ++j) h[j] = hn[j];
}

__global__ void __launch_bounds__(64, 2)
lstm3_kernel(const float* __restrict__ x,
             const float* __restrict__ wih0, const float* __restrict__ whh0,
             const float* __restrict__ bih0, const float* __restrict__ bhh0,
             const float* __restrict__ wih1, const float* __restrict__ whh1,
             const float* __restrict__ bih1, const float* __restrict__ bhh1,
             const float* __restrict__ wih2, const float* __restrict__ whh2,
             const float* __restrict__ bih2, const float* __restrict__ bhh2,
             const float* __restrict__ wfc,  const float* __restrict__ bfc,
             float* __restrict__ out, int B)
{
    int b = blockIdx.x * 64 + threadIdx.x;
    if (b >= B) return;

    float h0[HID], c0[HID], h1[HID], c1[HID], h2[HID], c2[HID];
#pragma unroll
    for (int j = 0; j < HID; ++j) {
        h0[j] = 0.f; c0[j] = 0.f;
        h1[j] = 0.f; c1[j] = 0.f;
        h2[j] = 0.f; c2[j] = 0.f;
    }

    const float* __restrict__ xp = x   + (size_t)b * TT;
    float* __restrict__       op = out + (size_t)b * TT;
    const float bf = bfc[0];

    for (int t = 0; t < TT; ++t) {
        float xt = xp[t];

        // ---- layer 0 (input dim = 1) ----
        {
            float hn[HID];
#pragma unroll
            for (int j = 0; j < HID; ++j) {
                float gi = bih0[j]         + bhh0[j];
                float gf = bih0[HID + j]   + bhh0[HID + j];
                float gg = bih0[2*HID + j] + bhh0[2*HID + j];
                float go = bih0[3*HID + j] + bhh0[3*HID + j];
                gi = fmaf(wih0[j],         xt, gi);
                gf = fmaf(wih0[HID + j],   xt, gf);
                gg = fmaf(wih0[2*HID + j], xt, gg);
                go = fmaf(wih0[3*HID + j], xt, go);
#pragma unroll
                for (int k = 0; k < HID; ++k) {
                    gi = fmaf(whh0[(j)*HID + k],         h0[k], gi);
                    gf = fmaf(whh0[(HID + j)*HID + k],   h0[k], gf);
                    gg = fmaf(whh0[(2*HID + j)*HID + k], h0[k], gg);
                    go = fmaf(whh0[(3*HID + j)*HID + k], h0[k], go);
                }
                float cn = fast_sigmoid(gf) * c0[j] + fast_sigmoid(gi) * fast_tanh(gg);
                c0[j]  = cn;
                hn[j]  = fast_sigmoid(go) * fast_tanh(cn);
            }
#pragma unroll
            for (int j = 0; j < HID; ++j) h0[j] = hn[j];
        }

        // ---- layer 1 ----
        cell15(wih1, whh1, bih1, bhh1, h0, h1, c1);
        // ---- layer 2 ----
        cell15(wih2, whh2, bih2, bhh2, h1, h2, c2);

        // ---- head: 15 -> 1 ----
        float p = bf;
#pragma unroll
        for (int k = 0; k < HID; ++k) p = fmaf(wfc[k], h2[k], p);
        op[t] = p;
    }
}

extern "C" void kernel_launch(void* const* d_in, const int* in_sizes, int n_in,
                              void* d_out, int out_size, void* d_ws, size_t ws_size,
                              hipStream_t stream)
{
    const float* x    = (const float*)d_in[0];
    const float* wih0 = (const float*)d_in[1];
    const float* whh0 = (const float*)d_in[2];
    const float* bih0 = (const float*)d_in[3];
    const float* bhh0 = (const float*)d_in[4];
    const float* wih1 = (const float*)d_in[5];
    const float* whh1 = (const float*)d_in[6];
    const float* bih1 = (const float*)d_in[7];
    const float* bhh1 = (const float*)d_in[8];
    const float* wih2 = (const float*)d_in[9];
    const float* whh2 = (const float*)d_in[10];
    const float* bih2 = (const float*)d_in[11];
    const float* bhh2 = (const float*)d_in[12];
    const float* wfc  = (const float*)d_in[13];
    const float* bfc  = (const float*)d_in[14];
    float* out = (float*)d_out;

    int B = in_sizes[0] / TT;           // 32768
    int blocks = (B + 63) / 64;         // 512 blocks x 64 threads = 1 thread/element

    lstm3_kernel<<<blocks, 64, 0, stream>>>(
        x, wih0, whh0, bih0, bhh0,
        wih1, whh1, bih1, bhh1,
        wih2, whh2, bih2, bhh2,
        wfc, bfc, out, B);
}

// Round 8
// 4415.557 us; speedup vs baseline: 4.3713x; 4.3713x over previous
//
#include <hip/hip_runtime.h>
#include <math.h>

// 3-layer LSTM (H=15) + head. B=32768, T=196.
// R8 = R2 resubmit (infra failures rounds 2-7; design still unmeasured).
//  - weights staged once into LDS (padded rows, b128 broadcast reads)
//  - x/out staged through LDS in 16-step chunks -> fully coalesced HBM traffic
//  - h/c state lives in LDS (j-major, lane-column -> conflict-free)
// One thread per batch element; 64-thread blocks (1 wave), 512 blocks.
// LDS audit: 51.2 KB static (< 64 KB); float4 ok (row stride 784 B = 49*16).

#define HID 15
#define TT  196
#define NB  64

__device__ __forceinline__ float sigm(float x) {
    return __builtin_amdgcn_rcpf(1.0f + __expf(-x));   // robust: exp->inf -> 0
}
__device__ __forceinline__ float tanh_f(float x) {
    float ax = fabsf(x);
    float e  = __expf(ax + ax);
    float t  = 1.0f - 2.0f * __builtin_amdgcn_rcpf(e + 1.0f);
    return copysignf(t, x);
}

// Layers 1/2: rows [32] = [wih(15),0 | whh(15),0]; HA/HB are 16-elem register
// arrays with element 15 == 0 (matches the zero pad in the weight rows).
#define LAYER12(SW, SB, HA, HB, SH, SC)                                   \
  do {                                                                    \
    _Pragma("unroll 3")                                                   \
    for (int j = 0; j < 15; ++j) {                                        \
      const float* wi = &SW[j][0];                                        \
      const float* wf = &SW[15+j][0];                                     \
      const float* wg = &SW[30+j][0];                                     \
      const float* wo = &SW[45+j][0];                                     \
      float gi = SB[j], gf = SB[15+j], gg = SB[30+j], go = SB[45+j];      \
      _Pragma("unroll")                                                   \
      for (int k = 0; k < 16; ++k) {                                      \
        gi = fmaf(wi[k], HA[k], gi);                                      \
        gf = fmaf(wf[k], HA[k], gf);                                      \
        gg = fmaf(wg[k], HA[k], gg);                                      \
        go = fmaf(wo[k], HA[k], go);                                      \
      }                                                                   \
      _Pragma("unroll")                                                   \
      for (int k = 0; k < 16; ++k) {                                      \
        gi = fmaf(wi[16+k], HB[k], gi);                                   \
        gf = fmaf(wf[16+k], HB[k], gf);                                   \
        gg = fmaf(wg[16+k], HB[k], gg);                                   \
        go = fmaf(wo[16+k], HB[k], go);                                   \
      }                                                                   \
      float cj = SC[j][tid];                                              \
      float cn = sigm(gf)*cj + sigm(gi)*tanh_f(gg);                       \
      SC[j][tid] = cn;                                                    \
      SH[j][tid] = sigm(go)*tanh_f(cn);                                   \
    }                                                                     \
  } while (0)

__global__ void __launch_bounds__(NB)
lstm3_lds(const float* __restrict__ x,
          const float* __restrict__ wih0, const float* __restrict__ whh0,
          const float* __restrict__ bih0, const float* __restrict__ bhh0,
          const float* __restrict__ wih1, const float* __restrict__ whh1,
          const float* __restrict__ bih1, const float* __restrict__ bhh1,
          const float* __restrict__ wih2, const float* __restrict__ whh2,
          const float* __restrict__ bih2, const float* __restrict__ bhh2,
          const float* __restrict__ wfc,  const float* __restrict__ bfc,
          float* __restrict__ out)
{
    __shared__ float s_w0[60][16];   // [wx | whh(15)]
    __shared__ float s_w1[60][32];   // [wih(15),0 | whh(15),0]
    __shared__ float s_w2[60][32];
    __shared__ float s_b0[60];
    __shared__ float s_b1[60];
    __shared__ float s_b2[60];
    __shared__ float s_head[16];
    __shared__ float s_h[3][15][NB]; // j-major: lane reads own column, conflict-free
    __shared__ float s_c[3][15][NB];
    __shared__ float s_xs[16][NB];
    __shared__ float s_os[16][NB];

    const int tid = threadIdx.x;

    // ---- one-time weight staging (tiny, L2/L3-cached across blocks) ----
    if (tid < 60) {
        int r = tid;
        s_w0[r][0] = wih0[r];
        #pragma unroll
        for (int k = 0; k < 15; ++k) s_w0[r][1+k] = whh0[r*15+k];
        #pragma unroll
        for (int k = 0; k < 15; ++k) { s_w1[r][k] = wih1[r*15+k]; s_w1[r][16+k] = whh1[r*15+k]; }
        s_w1[r][15] = 0.f; s_w1[r][31] = 0.f;
        #pragma unroll
        for (int k = 0; k < 15; ++k) { s_w2[r][k] = wih2[r*15+k]; s_w2[r][16+k] = whh2[r*15+k]; }
        s_w2[r][15] = 0.f; s_w2[r][31] = 0.f;
        s_b0[r] = bih0[r] + bhh0[r];
        s_b1[r] = bih1[r] + bhh1[r];
        s_b2[r] = bih2[r] + bhh2[r];
    }
    if (tid < 15) s_head[tid] = wfc[tid];
    if (tid == 15) s_head[15] = 0.f;
    // zero the recurrent state (LDS is garbage at launch)
    #pragma unroll
    for (int j = 0; j < 15; ++j) {
        s_h[0][j][tid] = 0.f; s_h[1][j][tid] = 0.f; s_h[2][j][tid] = 0.f;
        s_c[0][j][tid] = 0.f; s_c[1][j][tid] = 0.f; s_c[2][j][tid] = 0.f;
    }
    const float bhead = bfc[0];

    const float* __restrict__ xbase = x   + (size_t)blockIdx.x * NB * TT;
    float* __restrict__       obase = out + (size_t)blockIdx.x * NB * TT;

    for (int t0 = 0; t0 < TT; t0 += 16) {
        const int Lc  = (TT - t0 >= 16) ? 16 : (TT - t0);  // 16 or 4
        const int nch = Lc >> 2;                           // 4 or 1

        __syncthreads();  // protect s_xs/s_os reuse (also covers staging 1st iter)
        // stage x chunk: coalesced float4 reads -> LDS transpose
        for (int it = 0; it < nch; ++it) {
            int idx  = it * NB + tid;
            int brow = (nch == 4) ? (idx >> 2) : idx;
            int cc   = (nch == 4) ? (idx & 3) : 0;
            float4 v = *(const float4*)(xbase + (size_t)brow * TT + t0 + cc * 4);
            s_xs[cc*4+0][brow] = v.x; s_xs[cc*4+1][brow] = v.y;
            s_xs[cc*4+2][brow] = v.z; s_xs[cc*4+3][brow] = v.w;
        }
        __syncthreads();

        for (int tl = 0; tl < Lc; ++tl) {
            float xt = s_xs[tl][tid];

            // ---- layer 0 (input dim 1) ----
            float hB0[16];
            #pragma unroll
            for (int k = 0; k < 15; ++k) hB0[k] = s_h[0][k][tid];
            hB0[15] = 0.f;
            #pragma unroll 3
            for (int j = 0; j < 15; ++j) {
                const float* wi = &s_w0[j][0];
                const float* wf = &s_w0[15+j][0];
                const float* wg = &s_w0[30+j][0];
                const float* wo = &s_w0[45+j][0];
                float gi = s_b0[j], gf = s_b0[15+j], gg = s_b0[30+j], go = s_b0[45+j];
                gi = fmaf(wi[0], xt, gi);
                gf = fmaf(wf[0], xt, gf);
                gg = fmaf(wg[0], xt, gg);
                go = fmaf(wo[0], xt, go);
                #pragma unroll
                for (int k = 0; k < 15; ++k) {
                    gi = fmaf(wi[1+k], hB0[k], gi);
                    gf = fmaf(wf[1+k], hB0[k], gf);
                    gg = fmaf(wg[1+k], hB0[k], gg);
                    go = fmaf(wo[1+k], hB0[k], go);
                }
                float cj = s_c[0][j][tid];
                float cn = sigm(gf)*cj + sigm(gi)*tanh_f(gg);
                s_c[0][j][tid] = cn;
                s_h[0][j][tid] = sigm(go)*tanh_f(cn);
            }

            // ---- layer 1 ----
            {
                float hA[16], hB[16];
                #pragma unroll
                for (int k = 0; k < 15; ++k) hA[k] = s_h[0][k][tid];  // new h0
                hA[15] = 0.f;
                #pragma unroll
                for (int k = 0; k < 15; ++k) hB[k] = s_h[1][k][tid];  // old h1
                hB[15] = 0.f;
                LAYER12(s_w1, s_b1, hA, hB, s_h[1], s_c[1]);
            }

            // ---- layer 2 + head ----
            {
                float hA[16], hB[16];
                #pragma unroll
                for (int k = 0; k < 15; ++k) hA[k] = s_h[1][k][tid];  // new h1
                hA[15] = 0.f;
                #pragma unroll
                for (int k = 0; k < 15; ++k) hB[k] = s_h[2][k][tid];  // old h2
                hB[15] = 0.f;
                LAYER12(s_w2, s_b2, hA, hB, s_h[2], s_c[2]);

                float p = bhead;
                #pragma unroll
                for (int k = 0; k < 15; ++k) p = fmaf(s_head[k], s_h[2][k][tid], p);
                s_os[tl][tid] = p;
            }
        }
        __syncthreads();
        // flush out chunk: LDS -> coalesced float4 stores
        for (int it = 0; it < nch; ++it) {
            int idx  = it * NB + tid;
            int brow = (nch == 4) ? (idx >> 2) : idx;
            int cc   = (nch == 4) ? (idx & 3) : 0;
            float4 v;
            v.x = s_os[cc*4+0][brow]; v.y = s_os[cc*4+1][brow];
            v.z = s_os[cc*4+2][brow]; v.w = s_os[cc*4+3][brow];
            *(float4*)(obase + (size_t)brow * TT + t0 + cc * 4) = v;
        }
    }
}

extern "C" void kernel_launch(void* const* d_in, const int* in_sizes, int n_in,
                              void* d_out, int out_size, void* d_ws, size_t ws_size,
                              hipStream_t stream)
{
    const float* x    = (const float*)d_in[0];
    const float* wih0 = (const float*)d_in[1];
    const float* whh0 = (const float*)d_in[2];
    const float* bih0 = (const float*)d_in[3];
    const float* bhh0 = (const float*)d_in[4];
    const float* wih1 = (const float*)d_in[5];
    const float* whh1 = (const float*)d_in[6];
    const float* bih1 = (const float*)d_in[7];
    const float* bhh1 = (const float*)d_in[8];
    const float* wih2 = (const float*)d_in[9];
    const float* whh2 = (const float*)d_in[10];
    const float* bih2 = (const float*)d_in[11];
    const float* bhh2 = (const float*)d_in[12];
    const float* wfc  = (const float*)d_in[13];
    const float* bfc  = (const float*)d_in[14];
    float* out = (float*)d_out;

    int B = in_sizes[0] / TT;       // 32768
    int blocks = B / NB;            // 512

    lstm3_lds<<<blocks, NB, 0, stream>>>(
        x, wih0, whh0, bih0, bhh0,
        wih1, whh1, bih1, bhh1,
        wih2, whh2, bih2, bhh2,
        wfc, bfc, out);
}

// Round 13
// 2383.860 us; speedup vs baseline: 8.0969x; 1.8523x over previous
//
#include <hip/hip_runtime.h>
#include <math.h>

// 3-layer LSTM (H=15) + head. B=32768, T=196.
// R13 = R9 resubmit (broker timeouts R9-R12; redesign still unmeasured).
// R9: occupancy + scalar-path restructure (R8 measured: 4.42 ms, VALUBusy 25%,
// Occupancy 6% -> latency-bound, LDS weight-broadcast on the critical path).
//  - unit-split x4 ACROSS WAVES: wave (role) r owns units 4r..4r+3 of every
//    layer for the block's 64 elements. Weight addresses are wave-uniform
//    (forced via readfirstlane) -> compiler emits s_load; all weights (9.6 KB)
//    live in the 16 KB scalar K$ after warm-up. No VALU/LDS cost for weights.
//  - LDS only for h-exchange between roles: 19 ops + 3 barriers per step.
//  - 512 blocks x 256 thr = 2048 waves = 8/CU (2/SIMD) -> latency hiding.
//  - x/out staged through LDS in 16-step chunks (R8's verified pattern).
//  - role 3 computes a clamped duplicate of unit 14 -> writes unused s_h row
//    15; identical instruction stream in all waves, no OOB, no divergence.

#define HID 15
#define TT  196
#define NE  64          // elements per block (= lane)

__device__ __forceinline__ float sigm(float x) {
    return __builtin_amdgcn_rcpf(1.0f + __expf(-x));   // robust: exp->inf -> 0
}
__device__ __forceinline__ float tanh_f(float x) {
    float ax = fabsf(x);
    float e  = __expf(ax + ax);
    float t  = 1.0f - 2.0f * __builtin_amdgcn_rcpf(e + 1.0f);
    return copysignf(t, x);
}

// One layer step for the role's 4 units, input dim = HID (layers 1,2).
// hin: this layer's input vector (prev layer's NEW h). hrec: this layer's
// OWN h from t-1 (register copy). Writes new h to s_row, updates c.
__device__ __forceinline__ void layer_step(
    const float* __restrict__ wih, const float* __restrict__ whh,
    const float (&bs)[4][4], const int (&uu)[4], int u0,
    const float (&hin)[HID], const float (&hrec)[HID], float (&c)[4],
    float (*s_row)[NE], int lane)
{
#pragma unroll
    for (int i = 0; i < 4; ++i) {
        const int r0 = (0 * HID + uu[i]) * HID;
        const int r1 = (1 * HID + uu[i]) * HID;
        const int r2 = (2 * HID + uu[i]) * HID;
        const int r3 = (3 * HID + uu[i]) * HID;
        float a0 = bs[i][0], a1 = bs[i][1], a2 = bs[i][2], a3 = bs[i][3];
#pragma unroll
        for (int k = 0; k < HID; ++k) {
            const float v = hin[k];
            a0 = fmaf(wih[r0 + k], v, a0);
            a1 = fmaf(wih[r1 + k], v, a1);
            a2 = fmaf(wih[r2 + k], v, a2);
            a3 = fmaf(wih[r3 + k], v, a3);
        }
#pragma unroll
        for (int k = 0; k < HID; ++k) {
            const float v = hrec[k];
            a0 = fmaf(whh[r0 + k], v, a0);
            a1 = fmaf(whh[r1 + k], v, a1);
            a2 = fmaf(whh[r2 + k], v, a2);
            a3 = fmaf(whh[r3 + k], v, a3);
        }
        const float cn = sigm(a1) * c[i] + sigm(a0) * tanh_f(a2);
        c[i] = cn;
        s_row[u0 + i][lane] = sigm(a3) * tanh_f(cn);
    }
}

__global__ void __launch_bounds__(256, 2)
lstm3_role(const float* __restrict__ x,
           const float* __restrict__ wih0, const float* __restrict__ whh0,
           const float* __restrict__ bih0, const float* __restrict__ bhh0,
           const float* __restrict__ wih1, const float* __restrict__ whh1,
           const float* __restrict__ bih1, const float* __restrict__ bhh1,
           const float* __restrict__ wih2, const float* __restrict__ whh2,
           const float* __restrict__ bih2, const float* __restrict__ bhh2,
           const float* __restrict__ wfc,  const float* __restrict__ bfc,
           float* __restrict__ out)
{
    __shared__ float s_h[3][16][NE];   // h-exchange; row 15 = pad sink
    __shared__ float s_xs[16][NE];
    __shared__ float s_os[16][NE];

    const int tid  = threadIdx.x;
    const int lane = tid & 63;
    const int role = __builtin_amdgcn_readfirstlane(tid >> 6); // 0..3, SGPR
    const int u0   = role * 4;

    int uu[4];                         // clamped unit ids (role 3: 12,13,14,14)
#pragma unroll
    for (int i = 0; i < 4; ++i) {
        int u = u0 + i;
        uu[i] = (u < HID) ? u : (HID - 1);
    }

    // biases (uniform loads, once)
    float bs0[4][4], bs1[4][4], bs2[4][4];
#pragma unroll
    for (int i = 0; i < 4; ++i) {
#pragma unroll
        for (int g = 0; g < 4; ++g) {
            const int row = g * HID + uu[i];
            bs0[i][g] = bih0[row] + bhh0[row];
            bs1[i][g] = bih1[row] + bhh1[row];
            bs2[i][g] = bih2[row] + bhh2[row];
        }
    }
    float wf[HID];
#pragma unroll
    for (int k = 0; k < HID; ++k) wf[k] = wfc[k];
    const float bhead = bfc[0];

    // state
    float h0[HID], h1[HID], h2[HID], c0[4], c1[4], c2[4];
#pragma unroll
    for (int k = 0; k < HID; ++k) { h0[k] = 0.f; h1[k] = 0.f; h2[k] = 0.f; }
#pragma unroll
    for (int i = 0; i < 4; ++i) { c0[i] = 0.f; c1[i] = 0.f; c2[i] = 0.f; }

    const float* __restrict__ xbase = x   + (size_t)blockIdx.x * NE * TT;
    float* __restrict__       obase = out + (size_t)blockIdx.x * NE * TT;

    for (int t0 = 0; t0 < TT; t0 += 16) {
        const int Lc = (TT - t0 >= 16) ? 16 : (TT - t0);   // 16 or 4

        __syncthreads();   // protect s_xs/s_os reuse across chunks
        // stage x chunk (coalesced float4 -> LDS transpose), 256 threads
        if (Lc == 16) {
            const int brow = tid >> 2, cc = tid & 3;
            float4 v = *(const float4*)(xbase + (size_t)brow * TT + t0 + cc * 4);
            s_xs[cc * 4 + 0][brow] = v.x; s_xs[cc * 4 + 1][brow] = v.y;
            s_xs[cc * 4 + 2][brow] = v.z; s_xs[cc * 4 + 3][brow] = v.w;
        } else if (tid < NE) {
            float4 v = *(const float4*)(xbase + (size_t)tid * TT + t0);
            s_xs[0][tid] = v.x; s_xs[1][tid] = v.y;
            s_xs[2][tid] = v.z; s_xs[3][tid] = v.w;
        }
        __syncthreads();

        for (int tl = 0; tl < Lc; ++tl) {
            const float xt = s_xs[tl][lane];

            // ---- layer 0 (input dim 1) ----
#pragma unroll
            for (int i = 0; i < 4; ++i) {
                const int r0 = 0 * HID + uu[i];
                const int r1 = 1 * HID + uu[i];
                const int r2 = 2 * HID + uu[i];
                const int r3 = 3 * HID + uu[i];
                float a0 = bs0[i][0], a1 = bs0[i][1], a2 = bs0[i][2], a3 = bs0[i][3];
                a0 = fmaf(wih0[r0], xt, a0);
                a1 = fmaf(wih0[r1], xt, a1);
                a2 = fmaf(wih0[r2], xt, a2);
                a3 = fmaf(wih0[r3], xt, a3);
#pragma unroll
                for (int k = 0; k < HID; ++k) {
                    const float v = h0[k];
                    a0 = fmaf(whh0[r0 * HID + k], v, a0);
                    a1 = fmaf(whh0[r1 * HID + k], v, a1);
                    a2 = fmaf(whh0[r2 * HID + k], v, a2);
                    a3 = fmaf(whh0[r3 * HID + k], v, a3);
                }
                const float cn = sigm(a1) * c0[i] + sigm(a0) * tanh_f(a2);
                c0[i] = cn;
                s_h[0][u0 + i][lane] = sigm(a3) * tanh_f(cn);
            }
            __syncthreads();
#pragma unroll
            for (int k = 0; k < HID; ++k) h0[k] = s_h[0][k][lane];

            // ---- layer 1 ----
            layer_step(wih1, whh1, bs1, uu, u0, h0, h1, c1, s_h[1], lane);
            __syncthreads();
#pragma unroll
            for (int k = 0; k < HID; ++k) h1[k] = s_h[1][k][lane];

            // ---- layer 2 ----
            layer_step(wih2, whh2, bs2, uu, u0, h1, h2, c2, s_h[2], lane);
            __syncthreads();
#pragma unroll
            for (int k = 0; k < HID; ++k) h2[k] = s_h[2][k][lane];

            // ---- head (role 0 only; wave-uniform branch) ----
            if (role == 0) {
                float p = bhead;
#pragma unroll
                for (int k = 0; k < HID; ++k) p = fmaf(wf[k], h2[k], p);
                s_os[tl][lane] = p;
            }
        }
        __syncthreads();
        // flush out chunk (LDS -> coalesced float4), 256 threads
        if (Lc == 16) {
            const int brow = tid >> 2, cc = tid & 3;
            float4 v;
            v.x = s_os[cc * 4 + 0][brow]; v.y = s_os[cc * 4 + 1][brow];
            v.z = s_os[cc * 4 + 2][brow]; v.w = s_os[cc * 4 + 3][brow];
            *(float4*)(obase + (size_t)brow * TT + t0 + cc * 4) = v;
        } else if (tid < NE) {
            float4 v;
            v.x = s_os[0][tid]; v.y = s_os[1][tid];
            v.z = s_os[2][tid]; v.w = s_os[3][tid];
            *(float4*)(obase + (size_t)tid * TT + t0) = v;
        }
    }
}

extern "C" void kernel_launch(void* const* d_in, const int* in_sizes, int n_in,
                              void* d_out, int out_size, void* d_ws, size_t ws_size,
                              hipStream_t stream)
{
    const float* x    = (const float*)d_in[0];
    const float* wih0 = (const float*)d_in[1];
    const float* whh0 = (const float*)d_in[2];
    const float* bih0 = (const float*)d_in[3];
    const float* bhh0 = (const float*)d_in[4];
    const float* wih1 = (const float*)d_in[5];
    const float* whh1 = (const float*)d_in[6];
    const float* bih1 = (const float*)d_in[7];
    const float* bhh1 = (const float*)d_in[8];
    const float* wih2 = (const float*)d_in[9];
    const float* whh2 = (const float*)d_in[10];
    const float* bih2 = (const float*)d_in[11];
    const float* bhh2 = (const float*)d_in[12];
    const float* wfc  = (const float*)d_in[13];
    const float* bfc  = (const float*)d_in[14];
    float* out = (float*)d_out;

    int B = in_sizes[0] / TT;       // 32768
    int blocks = B / NE;            // 512 blocks x 256 threads = 2048 waves

    lstm3_role<<<blocks, 256, 0, stream>>>(
        x, wih0, whh0, bih0, bhh0,
        wih1, whh1, bih1, bhh1,
        wih2, whh2, bih2, bhh2,
        wfc, bfc, out);
}